// Round 1
// 502.490 us; speedup vs baseline: 1.2407x; 1.2407x over previous
//
#include <hip/hip_runtime.h>
#include <hip/hip_bf16.h>

// Problem constants
#define NN 384            // sequence dim
#define CZ 128            // channels
#define NH 4              // heads
#define HD 32             // head dim
#define MROWS (NN*NN)     // 147456 GEMM rows

typedef __hip_bfloat16 bf16;
typedef short bf16x8f __attribute__((ext_vector_type(8)));          // MFMA A/B operand (8 bf16)
typedef float f32x4 __attribute__((ext_vector_type(4)));            // MFMA C/D operand
typedef unsigned short u16x8 __attribute__((ext_vector_type(8)));   // staging store type

// bf16 <-> f32 helpers (bit-level, RNE)
__device__ __forceinline__ float b2f(unsigned short u) {
    return __uint_as_float(((unsigned)u) << 16);
}
__device__ __forceinline__ unsigned short f2b(float f) {
    unsigned u = __float_as_uint(f);
    return (unsigned short)((u + 0x7FFFu + ((u >> 16) & 1u)) >> 16);
}

// ---------------------------------------------------------------------------
// LayerNorm stats: one wave per row of 128; writes mu[r], rstd[r].
// ---------------------------------------------------------------------------
__global__ __launch_bounds__(256) void ln_stats_kernel(const float* __restrict__ z,
                                                       float* __restrict__ mu,
                                                       float* __restrict__ rstd) {
    const int wave = threadIdx.x >> 6;
    const int lane = threadIdx.x & 63;
    const int r = blockIdx.x * 4 + wave;
    const float* zr = z + (size_t)r * CZ;
    float x0 = zr[lane], x1 = zr[lane + 64];
    float sum = x0 + x1;
    float sq  = x0 * x0 + x1 * x1;
    #pragma unroll
    for (int o = 32; o > 0; o >>= 1) {
        sum += __shfl_xor(sum, o, 64);
        sq  += __shfl_xor(sq,  o, 64);
    }
    if (lane == 0) {
        const float m   = sum * (1.0f / CZ);
        const float var = sq * (1.0f / CZ) - m * m;
        mu[r]   = m;
        rstd[r] = rsqrtf(var + 1e-5f);
    }
}

// ---------------------------------------------------------------------------
// qkv GEMM on MFMA (bf16 inputs, f32 accumulate), fused LayerNorm on A:
//   qkv = LN(z) @ qkv_w + qkv_b, scattered as bf16 into qkv_t[t][h][n][i][d].
//
// Operands SWAPPED vs the math: mfma(A = W-cols frag, B = LN(z)-rows frag)
// so D[m = out-col][n = z-row].  C/D layout (verified m89): n = lane&15,
// m = (lane>>4)*4 + reg  ->  the 4 acc regs are 4 CONSECUTIVE out-cols
// (d-dim of qkv_t) -> single ushort4 store per fragment.
//
// Tile: 128 z-rows x 64 out-cols, K = 128 staged once (no K loop tiling).
// Waves 2x2: wcol in {0,1} covers 32 cols, wrow in {0,1} covers 64 rows.
// LN(z) tile -> LDS bf16, XOR-swizzled (chunk' = chunk ^ (row&7)) to kill
// the 16-way bank conflict a linear [row][128] layout has on ds_read_b128.
// W fragments load direct global->reg (W = 196 KB, L2-hot; 16-col-coalesced).
// LDS: 32 KB -> 4-5 blocks/CU.
// ---------------------------------------------------------------------------
__global__ __launch_bounds__(256) void qkv_gemm_mfma_kernel(const float* __restrict__ z,
                                                            const float* __restrict__ mu,
                                                            const float* __restrict__ rstd,
                                                            const float* __restrict__ lnw,
                                                            const float* __restrict__ lnb,
                                                            const float* __restrict__ W,
                                                            const float* __restrict__ bias,
                                                            unsigned short* __restrict__ qkv_t) {
    __shared__ unsigned short Zt[128 * 128];   // 32 KB: slot16 (row, c') holds k-chunk c'^(row&7)

    const int tid = threadIdx.x;
    const int w = tid >> 6;
    const int l = tid & 63;
    const int col0 = blockIdx.x * 64;    // out-col block (x fastest: W panel + z rows L2-hot)
    const int row0 = blockIdx.y * 128;   // z-row block
    const int wcol = w & 1;
    const int wrow = w >> 1;
    const int lm = l & 15;
    const int lq = l >> 4;

    // ---- stage LN(z) tile into swizzled LDS as bf16 ----
    #pragma unroll
    for (int it = 0; it < 8; it++) {
        const int s = it * 256 + tid;          // 2048 16B slots
        const int r = s >> 4;
        const int c = (s & 15) ^ (r & 7);      // inverse swizzle on source chunk
        const int k0 = c * 8;
        const int grow = row0 + r;
        const float m  = mu[grow];
        const float rs = rstd[grow];
        const float4 z0 = *(const float4*)(z + (size_t)grow * CZ + k0);
        const float4 z1 = *(const float4*)(z + (size_t)grow * CZ + k0 + 4);
        const float4 w0 = *(const float4*)(lnw + k0);
        const float4 w1 = *(const float4*)(lnw + k0 + 4);
        const float4 b0 = *(const float4*)(lnb + k0);
        const float4 b1 = *(const float4*)(lnb + k0 + 4);
        u16x8 pk;
        pk[0] = f2b((z0.x - m) * rs * w0.x + b0.x);
        pk[1] = f2b((z0.y - m) * rs * w0.y + b0.y);
        pk[2] = f2b((z0.z - m) * rs * w0.z + b0.z);
        pk[3] = f2b((z0.w - m) * rs * w0.w + b0.w);
        pk[4] = f2b((z1.x - m) * rs * w1.x + b1.x);
        pk[5] = f2b((z1.y - m) * rs * w1.y + b1.y);
        pk[6] = f2b((z1.z - m) * rs * w1.z + b1.z);
        pk[7] = f2b((z1.w - m) * rs * w1.w + b1.w);
        *(u16x8*)&Zt[s * 8] = pk;
    }

    // ---- W fragments direct global->reg (overlaps with barrier wait) ----
    // A-frag layout: m = lane&15 (out-col), k = kk*32 + (lane>>4)*8 + j.
    // Lanes 0..15 read 16 consecutive cols at same k -> 64B-line coalesced.
    bf16x8f a[2][4];
    #pragma unroll
    for (int fm = 0; fm < 2; fm++) {
        const int gcol = col0 + wcol * 32 + fm * 16 + lm;
        #pragma unroll
        for (int kk = 0; kk < 4; kk++) {
            const int kb = kk * 32 + lq * 8;
            #pragma unroll
            for (int j = 0; j < 8; j++)
                a[fm][kk][j] = (short)f2b(W[(size_t)(kb + j) * (3 * CZ) + gcol]);
        }
    }

    __syncthreads();

    // ---- MFMA main: 4 k-steps x (2 col-frags x 4 row-frags) = 32 MFMA/wave
    f32x4 acc[2][4];
    #pragma unroll
    for (int fm = 0; fm < 2; fm++)
        #pragma unroll
        for (int fn = 0; fn < 4; fn++)
            acc[fm][fn] = (f32x4){0.0f, 0.0f, 0.0f, 0.0f};

    #pragma unroll
    for (int kk = 0; kk < 4; kk++) {
        bf16x8f bf[4];
        #pragma unroll
        for (int fn = 0; fn < 4; fn++) {
            const int r = wrow * 64 + fn * 16 + lm;
            const int ch = (kk * 4 + lq) ^ (r & 7);     // swizzled chunk index
            bf[fn] = *(const bf16x8f*)&Zt[(r * 16 + ch) * 8];
        }
        #pragma unroll
        for (int fm = 0; fm < 2; fm++)
            #pragma unroll
            for (int fn = 0; fn < 4; fn++)
                acc[fm][fn] = __builtin_amdgcn_mfma_f32_16x16x32_bf16(a[fm][kk], bf[fn],
                                                                      acc[fm][fn], 0, 0, 0);
    }

    // ---- epilogue: bias + pack + scatter (4 consecutive d per ushort4) ----
    #pragma unroll
    for (int fm = 0; fm < 2; fm++) {
        const int gc = col0 + wcol * 32 + fm * 16 + lq * 4;   // out-col of reg 0
        const float4 b4 = *(const float4*)(bias + gc);
        const int t  = gc >> 7;
        const int hh = (gc & 127) >> 5;
        const int d0 = gc & 31;
        const size_t colbase = (size_t)((t * NH + hh) * NN) * (NN * HD) + d0;
        #pragma unroll
        for (int fn = 0; fn < 4; fn++) {
            const int grow = row0 + wrow * 64 + fn * 16 + lm;  // = i*NN + n
            const int i  = grow / NN;
            const int n0 = grow - i * NN;
            const size_t idx = colbase + (size_t)n0 * (NN * HD) + (size_t)i * HD;
            ushort4 pk;
            pk.x = f2b(acc[fm][fn][0] + b4.x);
            pk.y = f2b(acc[fm][fn][1] + b4.y);
            pk.z = f2b(acc[fm][fn][2] + b4.z);
            pk.w = f2b(acc[fm][fn][3] + b4.w);
            *(ushort4*)(qkv_t + idx) = pk;
        }
    }
}

// ---------------------------------------------------------------------------
// MFMA attention per (n,h). S[i,j]=scale*q_i.k_j; softmax over i (per-col j);
// O[i,:] = sum_j P[i,j] v[j,:].
// Pass 1: S tiles via mfma_16x16x32 (K=32=HD), col sums of exp -> 1/s_j.
// Pass 2: S^T tiles (A=K,B=Q) -> P written to per-wave LDS scratch -> read
//         back as PV A-frag; V pre-swizzled into B-frag layout with 1/s
//         folded in at staging (quartered to fit LDS).
// LDS: Qf 24K + Kf 24K + Vf 6K + sst 1.5K + Pscr 5K = 62.0 KB -> 2 blocks/CU.
// ---------------------------------------------------------------------------
__global__ __launch_bounds__(256) void attn_mfma_kernel(const unsigned short* __restrict__ qkv_t,
                                                        float* __restrict__ attn_out) {
    __shared__ unsigned short Qf[24 * 512];   // frag-order: tile*512 + lane*8
    __shared__ unsigned short Kf[24 * 512];
    __shared__ unsigned short Vf[3 * 2 * 512]; // [chunk_local][dhalf][lane*8]
    __shared__ float sst[NN];                  // 1/s_j
    __shared__ unsigned short Pscr[4][16][40]; // per-wave P tile, pitch 40

    const int b = blockIdx.x;
    const int n = b >> 2;
    const int h = b & 3;
    const int tid = threadIdx.x;
    const int w = tid >> 6;        // wave 0..3
    const int l = tid & 63;        // lane
    const int q = l >> 4;          // quad 0..3
    const int m = l & 15;          // low lane bits
    const size_t base_q = (size_t)((0 * NH + h) * NN + n) * (NN * HD);
    const size_t base_k = (size_t)((1 * NH + h) * NN + n) * (NN * HD);
    const size_t base_v = (size_t)((2 * NH + h) * NN + n) * (NN * HD);
    const float SCALE = 0.17677669529663687f;  // 1/sqrt(32)
    const f32x4 zero = {0.0f, 0.0f, 0.0f, 0.0f};

    // ---- Stage Q and K into fragment-order LDS (3072 16B slots) ----
    #pragma unroll
    for (int it = 0; it < 12; it++) {
        const int s = tid + it * 256;
        const int isK = s >= 1536;
        const int slot = isK ? (s - 1536) : s;   // 1536 is not pow2; & 1535 would be wrong
        const int t  = slot >> 6;
        const int l2 = slot & 63;
        const int row = t * 16 + (l2 & 15);
        const int off8 = (l2 >> 4) * 8;
        const u16x8 raw = *(const u16x8*)(qkv_t + (isK ? base_k : base_q) +
                                         (size_t)row * HD + off8);
        unsigned short* dst = (isK ? Kf : Qf) + slot * 8;
        *(u16x8*)dst = raw;
    }
    __syncthreads();

    // ---- Pass 1: column sums of exp(scale*S) -> sst[j] = 1/s_j ----
    for (int tt = 0; tt < 6; tt++) {
        const int jt = w + 4 * tt;
        const bf16x8f kb = *(const bf16x8f*)&Kf[jt * 512 + l * 8];
        float s0 = 0.f, s1 = 0.f, s2 = 0.f, s3 = 0.f;
        for (int it = 0; it < 24; it++) {
            const bf16x8f qa = *(const bf16x8f*)&Qf[it * 512 + l * 8];
            const f32x4 c = __builtin_amdgcn_mfma_f32_16x16x32_bf16(qa, kb, zero, 0, 0, 0);
            s0 += __expf(c[0] * SCALE);
            s1 += __expf(c[1] * SCALE);
            s2 += __expf(c[2] * SCALE);
            s3 += __expf(c[3] * SCALE);
        }
        float s = s0 + s1 + s2 + s3;
        s += __shfl_xor(s, 16, 64);
        s += __shfl_xor(s, 32, 64);
        if (q == 0) sst[jt * 16 + m] = 1.0f / s;
    }
    __syncthreads();

    // ---- Pass 2: O = P @ V' (V' = V * 1/s), V staged in quarters ----
    f32x4 oacc[6][2];
    #pragma unroll
    for (int tt = 0; tt < 6; tt++) {
        oacc[tt][0] = zero;
        oacc[tt][1] = zero;
    }

    for (int vr = 0; vr < 4; vr++) {
        // stage Vf: 384 slots (3 chunks x 2 dhalves x 64 lanes)
        for (int s = tid; s < 384; s += 256) {
            const int cl = s >> 7;           // 0..2
            const int dh = (s >> 6) & 1;
            const int l2 = s & 63;
            const int cg = vr * 3 + cl;
            const int j0 = cg * 32 + (l2 >> 4) * 8;
            const int d  = dh * 16 + (l2 & 15);
            ushort4 pk0, pk1;
            {
                const unsigned short* vp = qkv_t + base_v + (size_t)j0 * HD + d;
                pk0.x = f2b(b2f(vp[0 * HD]) * sst[j0 + 0]);
                pk0.y = f2b(b2f(vp[1 * HD]) * sst[j0 + 1]);
                pk0.z = f2b(b2f(vp[2 * HD]) * sst[j0 + 2]);
                pk0.w = f2b(b2f(vp[3 * HD]) * sst[j0 + 3]);
                pk1.x = f2b(b2f(vp[4 * HD]) * sst[j0 + 4]);
                pk1.y = f2b(b2f(vp[5 * HD]) * sst[j0 + 5]);
                pk1.z = f2b(b2f(vp[6 * HD]) * sst[j0 + 6]);
                pk1.w = f2b(b2f(vp[7 * HD]) * sst[j0 + 7]);
            }
            unsigned short* dst = Vf + ((cl * 2 + dh) * 64 + l2) * 8;
            *(ushort4*)(dst)     = pk0;
            *(ushort4*)(dst + 4) = pk1;
        }
        __syncthreads();

        for (int cl = 0; cl < 3; cl++) {
            const int cg = vr * 3 + cl;
            const bf16x8f ka0 = *(const bf16x8f*)&Kf[(cg * 2 + 0) * 512 + l * 8];
            const bf16x8f ka1 = *(const bf16x8f*)&Kf[(cg * 2 + 1) * 512 + l * 8];
            const bf16x8f vb0 = *(const bf16x8f*)&Vf[((cl * 2 + 0) * 64 + l) * 8];
            const bf16x8f vb1 = *(const bf16x8f*)&Vf[((cl * 2 + 1) * 64 + l) * 8];
            #pragma unroll
            for (int tt = 0; tt < 6; tt++) {
                const int it = w + 4 * tt;
                const bf16x8f qb = *(const bf16x8f*)&Qf[it * 512 + l * 8];
                // S^T tiles: rows j (quad*4+reg), cols i (m)
                const f32x4 sT0 = __builtin_amdgcn_mfma_f32_16x16x32_bf16(ka0, qb, zero, 0, 0, 0);
                const f32x4 sT1 = __builtin_amdgcn_mfma_f32_16x16x32_bf16(ka1, qb, zero, 0, 0, 0);
                // P = exp(scale*S): lane (q,m) holds P[i=m][j=q*4+r] (+16 for sT1)
                ushort4 p0, p1;
                p0.x = f2b(__expf(sT0[0] * SCALE));
                p0.y = f2b(__expf(sT0[1] * SCALE));
                p0.z = f2b(__expf(sT0[2] * SCALE));
                p0.w = f2b(__expf(sT0[3] * SCALE));
                p1.x = f2b(__expf(sT1[0] * SCALE));
                p1.y = f2b(__expf(sT1[1] * SCALE));
                p1.z = f2b(__expf(sT1[2] * SCALE));
                p1.w = f2b(__expf(sT1[3] * SCALE));
                *(ushort4*)&Pscr[w][m][q * 4]      = p0;
                *(ushort4*)&Pscr[w][m][16 + q * 4] = p1;
                // Same-wave LDS RAW (cross-lane within wave): fence + drain.
                __asm__ volatile("" ::: "memory");
                __builtin_amdgcn_s_waitcnt(0xC07F);   // lgkmcnt(0), vm/exp don't-care
                // read back as PV A-frag: P[i=m][j=q*8..q*8+7]
                const bf16x8f pa = *(const bf16x8f*)&Pscr[w][m][q * 8];
                __asm__ volatile("" ::: "memory");
                oacc[tt][0] = __builtin_amdgcn_mfma_f32_16x16x32_bf16(pa, vb0, oacc[tt][0], 0, 0, 0);
                oacc[tt][1] = __builtin_amdgcn_mfma_f32_16x16x32_bf16(pa, vb1, oacc[tt][1], 0, 0, 0);
            }
        }
        __syncthreads();
    }

    // ---- Store O: rows i = it*16 + q*4 + r, col d = dt*16 + m ----
    #pragma unroll
    for (int tt = 0; tt < 6; tt++) {
        const int it = w + 4 * tt;
        #pragma unroll
        for (int dt = 0; dt < 2; dt++) {
            #pragma unroll
            for (int r = 0; r < 4; r++) {
                const int i = it * 16 + q * 4 + r;
                attn_out[((size_t)i * NN + n) * CZ + h * HD + dt * 16 + m] = oacc[tt][dt][r];
            }
        }
    }
}

// ---------------------------------------------------------------------------
// Final dual GEMM (block owns 64 rows exclusively; in-place on out):
//   out = z + sigmoid(LN(z)@gate_w+gate_b) * (attn@out_w + out_b)
// ---------------------------------------------------------------------------
__global__ __launch_bounds__(256) void final_kernel(const float* __restrict__ z,
                                                    const float* __restrict__ mu,
                                                    const float* __restrict__ rstd,
                                                    const float* __restrict__ lnw,
                                                    const float* __restrict__ lnb,
                                                    const float* __restrict__ gate_w,
                                                    const float* __restrict__ gate_b,
                                                    const float* __restrict__ out_w,
                                                    const float* __restrict__ out_b,
                                                    float* __restrict__ out) {
    __shared__ float As1[32][68];
    __shared__ float As2[32][68];
    __shared__ float Bs1[32][132];
    __shared__ float Bs2[32][132];

    const int tid = threadIdx.x;
    const int tx = tid & 31;
    const int ty = tid >> 5;
    const int row0 = blockIdx.x * 64;

    float acc1[8][4], acc2[8][4];
    #pragma unroll
    for (int i = 0; i < 8; i++)
        #pragma unroll
        for (int j = 0; j < 4; j++) { acc1[i][j] = 0.0f; acc2[i][j] = 0.0f; }

    for (int kt = 0; kt < 128; kt += 32) {
        #pragma unroll
        for (int l = tid; l < 512; l += 256) {
            const int ar = l >> 3;
            const int ac4 = l & 7;
            const int row = row0 + ar;
            const int c = kt + ac4 * 4;
            const size_t gi = (size_t)row * CZ + c;
            const float4 zv = *(const float4*)(z + gi);
            const float4 av = *(const float4*)(out + gi);
            const float m  = mu[row];
            const float rs = rstd[row];
            const float4 w4 = *(const float4*)(lnw + c);
            const float4 b4 = *(const float4*)(lnb + c);
            As1[ac4 * 4 + 0][ar] = (zv.x - m) * rs * w4.x + b4.x;
            As1[ac4 * 4 + 1][ar] = (zv.y - m) * rs * w4.y + b4.y;
            As1[ac4 * 4 + 2][ar] = (zv.z - m) * rs * w4.z + b4.z;
            As1[ac4 * 4 + 3][ar] = (zv.w - m) * rs * w4.w + b4.w;
            As2[ac4 * 4 + 0][ar] = av.x;
            As2[ac4 * 4 + 1][ar] = av.y;
            As2[ac4 * 4 + 2][ar] = av.z;
            As2[ac4 * 4 + 3][ar] = av.w;
        }
        #pragma unroll
        for (int l = tid; l < 1024; l += 256) {
            const int br = l >> 5;
            const int bc4 = l & 31;
            const size_t gb = (size_t)(kt + br) * CZ + bc4 * 4;
            *(float4*)&Bs1[br][bc4 * 4] = *(const float4*)(gate_w + gb);
            *(float4*)&Bs2[br][bc4 * 4] = *(const float4*)(out_w + gb);
        }
        __syncthreads();
        #pragma unroll
        for (int kk = 0; kk < 32; kk++) {
            const float4 a1a = *(const float4*)&As1[kk][ty * 8];
            const float4 a1b = *(const float4*)&As1[kk][ty * 8 + 4];
            const float4 a2a = *(const float4*)&As2[kk][ty * 8];
            const float4 a2b = *(const float4*)&As2[kk][ty * 8 + 4];
            const float4 b1 = *(const float4*)&Bs1[kk][tx * 4];
            const float4 b2 = *(const float4*)&Bs2[kk][tx * 4];
            const float a1[8] = {a1a.x, a1a.y, a1a.z, a1a.w, a1b.x, a1b.y, a1b.z, a1b.w};
            const float a2[8] = {a2a.x, a2a.y, a2a.z, a2a.w, a2b.x, a2b.y, a2b.z, a2b.w};
            #pragma unroll
            for (int rr = 0; rr < 8; rr++) {
                acc1[rr][0] += a1[rr] * b1.x; acc1[rr][1] += a1[rr] * b1.y;
                acc1[rr][2] += a1[rr] * b1.z; acc1[rr][3] += a1[rr] * b1.w;
                acc2[rr][0] += a2[rr] * b2.x; acc2[rr][1] += a2[rr] * b2.y;
                acc2[rr][2] += a2[rr] * b2.z; acc2[rr][3] += a2[rr] * b2.w;
            }
        }
        __syncthreads();
    }

    const int col = tx * 4;
    const float4 gb = *(const float4*)(gate_b + col);
    const float4 ob = *(const float4*)(out_b + col);
    #pragma unroll
    for (int rr = 0; rr < 8; rr++) {
        const int row = row0 + ty * 8 + rr;
        const size_t idx = (size_t)row * CZ + col;
        const float4 z4 = *(const float4*)(z + idx);
        float4 o;
        o.x = z4.x + (1.0f / (1.0f + __expf(-(acc1[rr][0] + gb.x)))) * (acc2[rr][0] + ob.x);
        o.y = z4.y + (1.0f / (1.0f + __expf(-(acc1[rr][1] + gb.y)))) * (acc2[rr][1] + ob.y);
        o.z = z4.z + (1.0f / (1.0f + __expf(-(acc1[rr][2] + gb.z)))) * (acc2[rr][2] + ob.z);
        o.w = z4.w + (1.0f / (1.0f + __expf(-(acc1[rr][3] + gb.w)))) * (acc2[rr][3] + ob.w);
        *(float4*)(out + idx) = o;
    }
}

// ---------------------------------------------------------------------------
extern "C" void kernel_launch(void* const* d_in, const int* in_sizes, int n_in,
                              void* d_out, int out_size, void* d_ws, size_t ws_size,
                              hipStream_t stream) {
    const float* z      = (const float*)d_in[0];
    const float* ln_w   = (const float*)d_in[1];
    const float* ln_b   = (const float*)d_in[2];
    const float* qkv_w  = (const float*)d_in[3];
    const float* qkv_b  = (const float*)d_in[4];
    const float* out_w  = (const float*)d_in[5];
    const float* out_b  = (const float*)d_in[6];
    const float* gate_w = (const float*)d_in[7];
    const float* gate_b = (const float*)d_in[8];
    float* out = (float*)d_out;

    // Workspace: mu + rstd (f32) + qkv_t (bf16) ~= 114 MiB
    float* ws = (float*)d_ws;
    float* mu_buf   = ws;
    float* rstd_buf = ws + MROWS;
    unsigned short* qkv_t = (unsigned short*)(ws + 2 * MROWS);

    ln_stats_kernel<<<MROWS / 4, 256, 0, stream>>>(z, mu_buf, rstd_buf);
    qkv_gemm_mfma_kernel<<<dim3(6, MROWS / 128), 256, 0, stream>>>(z, mu_buf, rstd_buf,
                                                                   ln_w, ln_b, qkv_w, qkv_b, qkv_t);
    attn_mfma_kernel<<<NN * NH, 256, 0, stream>>>(qkv_t, out);
    final_kernel<<<MROWS / 64, 256, 0, stream>>>(z, mu_buf, rstd_buf, ln_w, ln_b,
                                                 gate_w, gate_b, out_w, out_b, out);
}

// Round 2
// 417.868 us; speedup vs baseline: 1.4920x; 1.2025x over previous
//
#include <hip/hip_runtime.h>
#include <hip/hip_bf16.h>

// Problem constants
#define NN 384            // sequence dim
#define CZ 128            // channels
#define NH 4              // heads
#define HD 32             // head dim
#define MROWS (NN*NN)     // 147456 GEMM rows

typedef __hip_bfloat16 bf16;
typedef short bf16x8f __attribute__((ext_vector_type(8)));          // MFMA A/B operand (8 bf16)
typedef float f32x4 __attribute__((ext_vector_type(4)));            // MFMA C/D operand
typedef unsigned short u16x8 __attribute__((ext_vector_type(8)));   // staging store type

// bf16 <-> f32 helpers (bit-level, RNE)
__device__ __forceinline__ float b2f(unsigned short u) {
    return __uint_as_float(((unsigned)u) << 16);
}
__device__ __forceinline__ unsigned short f2b(float f) {
    unsigned u = __float_as_uint(f);
    return (unsigned short)((u + 0x7FFFu + ((u >> 16) & 1u)) >> 16);
}

// ---------------------------------------------------------------------------
// LayerNorm stats: one wave per row of 128; writes mu[r], rstd[r].
// ---------------------------------------------------------------------------
__global__ __launch_bounds__(256) void ln_stats_kernel(const float* __restrict__ z,
                                                       float* __restrict__ mu,
                                                       float* __restrict__ rstd) {
    const int wave = threadIdx.x >> 6;
    const int lane = threadIdx.x & 63;
    const int r = blockIdx.x * 4 + wave;
    const float* zr = z + (size_t)r * CZ;
    float x0 = zr[lane], x1 = zr[lane + 64];
    float sum = x0 + x1;
    float sq  = x0 * x0 + x1 * x1;
    #pragma unroll
    for (int o = 32; o > 0; o >>= 1) {
        sum += __shfl_xor(sum, o, 64);
        sq  += __shfl_xor(sq,  o, 64);
    }
    if (lane == 0) {
        const float m   = sum * (1.0f / CZ);
        const float var = sq * (1.0f / CZ) - m * m;
        mu[r]   = m;
        rstd[r] = rsqrtf(var + 1e-5f);
    }
}

// ---------------------------------------------------------------------------
// qkv GEMM on MFMA (bf16 inputs, f32 accumulate), fused LayerNorm on A:
//   qkv = LN(z) @ qkv_w + qkv_b, scattered as bf16 into qkv_t[t][h][n][i][d].
// Operands SWAPPED: mfma(A = W-cols frag, B = LN(z)-rows frag) so the 4 acc
// regs are 4 CONSECUTIVE out-cols -> single ushort4 store per fragment.
// Tile: 128 z-rows x 64 out-cols, K = 128 staged once.  LN(z) tile -> LDS
// bf16, XOR-swizzled (chunk' = chunk ^ (row&7)).  W frags direct global->reg.
// LDS: 32 KB.
// ---------------------------------------------------------------------------
__global__ __launch_bounds__(256) void qkv_gemm_mfma_kernel(const float* __restrict__ z,
                                                            const float* __restrict__ mu,
                                                            const float* __restrict__ rstd,
                                                            const float* __restrict__ lnw,
                                                            const float* __restrict__ lnb,
                                                            const float* __restrict__ W,
                                                            const float* __restrict__ bias,
                                                            unsigned short* __restrict__ qkv_t) {
    __shared__ unsigned short Zt[128 * 128];   // 32 KB: slot16 (row, c') holds k-chunk c'^(row&7)

    const int tid = threadIdx.x;
    const int w = tid >> 6;
    const int l = tid & 63;
    const int col0 = blockIdx.x * 64;    // out-col block (x fastest: W panel + z rows L2-hot)
    const int row0 = blockIdx.y * 128;   // z-row block
    const int wcol = w & 1;
    const int wrow = w >> 1;
    const int lm = l & 15;
    const int lq = l >> 4;

    // ---- stage LN(z) tile into swizzled LDS as bf16 ----
    #pragma unroll
    for (int it = 0; it < 8; it++) {
        const int s = it * 256 + tid;          // 2048 16B slots
        const int r = s >> 4;
        const int c = (s & 15) ^ (r & 7);      // inverse swizzle on source chunk
        const int k0 = c * 8;
        const int grow = row0 + r;
        const float m  = mu[grow];
        const float rs = rstd[grow];
        const float4 z0 = *(const float4*)(z + (size_t)grow * CZ + k0);
        const float4 z1 = *(const float4*)(z + (size_t)grow * CZ + k0 + 4);
        const float4 w0 = *(const float4*)(lnw + k0);
        const float4 w1 = *(const float4*)(lnw + k0 + 4);
        const float4 b0 = *(const float4*)(lnb + k0);
        const float4 b1 = *(const float4*)(lnb + k0 + 4);
        u16x8 pk;
        pk[0] = f2b((z0.x - m) * rs * w0.x + b0.x);
        pk[1] = f2b((z0.y - m) * rs * w0.y + b0.y);
        pk[2] = f2b((z0.z - m) * rs * w0.z + b0.z);
        pk[3] = f2b((z0.w - m) * rs * w0.w + b0.w);
        pk[4] = f2b((z1.x - m) * rs * w1.x + b1.x);
        pk[5] = f2b((z1.y - m) * rs * w1.y + b1.y);
        pk[6] = f2b((z1.z - m) * rs * w1.z + b1.z);
        pk[7] = f2b((z1.w - m) * rs * w1.w + b1.w);
        *(u16x8*)&Zt[s * 8] = pk;
    }

    // ---- W fragments direct global->reg ----
    bf16x8f a[2][4];
    #pragma unroll
    for (int fm = 0; fm < 2; fm++) {
        const int gcol = col0 + wcol * 32 + fm * 16 + lm;
        #pragma unroll
        for (int kk = 0; kk < 4; kk++) {
            const int kb = kk * 32 + lq * 8;
            #pragma unroll
            for (int j = 0; j < 8; j++)
                a[fm][kk][j] = (short)f2b(W[(size_t)(kb + j) * (3 * CZ) + gcol]);
        }
    }

    __syncthreads();

    // ---- MFMA main: 4 k-steps x (2 col-frags x 4 row-frags) = 32 MFMA/wave
    f32x4 acc[2][4];
    #pragma unroll
    for (int fm = 0; fm < 2; fm++)
        #pragma unroll
        for (int fn = 0; fn < 4; fn++)
            acc[fm][fn] = (f32x4){0.0f, 0.0f, 0.0f, 0.0f};

    #pragma unroll
    for (int kk = 0; kk < 4; kk++) {
        bf16x8f bf[4];
        #pragma unroll
        for (int fn = 0; fn < 4; fn++) {
            const int r = wrow * 64 + fn * 16 + lm;
            const int ch = (kk * 4 + lq) ^ (r & 7);     // swizzled chunk index
            bf[fn] = *(const bf16x8f*)&Zt[(r * 16 + ch) * 8];
        }
        #pragma unroll
        for (int fm = 0; fm < 2; fm++)
            #pragma unroll
            for (int fn = 0; fn < 4; fn++)
                acc[fm][fn] = __builtin_amdgcn_mfma_f32_16x16x32_bf16(a[fm][kk], bf[fn],
                                                                      acc[fm][fn], 0, 0, 0);
    }

    // ---- epilogue: bias + pack + scatter (4 consecutive d per ushort4) ----
    #pragma unroll
    for (int fm = 0; fm < 2; fm++) {
        const int gc = col0 + wcol * 32 + fm * 16 + lq * 4;   // out-col of reg 0
        const float4 b4 = *(const float4*)(bias + gc);
        const int t  = gc >> 7;
        const int hh = (gc & 127) >> 5;
        const int d0 = gc & 31;
        const size_t colbase = (size_t)((t * NH + hh) * NN) * (NN * HD) + d0;
        #pragma unroll
        for (int fn = 0; fn < 4; fn++) {
            const int grow = row0 + wrow * 64 + fn * 16 + lm;  // = i*NN + n
            const int i  = grow / NN;
            const int n0 = grow - i * NN;
            const size_t idx = colbase + (size_t)n0 * (NN * HD) + (size_t)i * HD;
            ushort4 pk;
            pk.x = f2b(acc[fm][fn][0] + b4.x);
            pk.y = f2b(acc[fm][fn][1] + b4.y);
            pk.z = f2b(acc[fm][fn][2] + b4.z);
            pk.w = f2b(acc[fm][fn][3] + b4.w);
            *(ushort4*)(qkv_t + idx) = pk;
        }
    }
}

// ---------------------------------------------------------------------------
// MFMA attention per (n,h). S[i,j]=scale*q_i.k_j; softmax over i (per-col j);
// O[i,:] = sum_j P[i,j] v[j,:].
// LDS: Qf 24K + Kf 24K + Vf 6K + sst 1.5K + Pscr 5K = 62.0 KB -> 2 blocks/CU.
// ---------------------------------------------------------------------------
__global__ __launch_bounds__(256) void attn_mfma_kernel(const unsigned short* __restrict__ qkv_t,
                                                        float* __restrict__ attn_out) {
    __shared__ unsigned short Qf[24 * 512];   // frag-order: tile*512 + lane*8
    __shared__ unsigned short Kf[24 * 512];
    __shared__ unsigned short Vf[3 * 2 * 512]; // [chunk_local][dhalf][lane*8]
    __shared__ float sst[NN];                  // 1/s_j
    __shared__ unsigned short Pscr[4][16][40]; // per-wave P tile, pitch 40

    const int b = blockIdx.x;
    const int n = b >> 2;
    const int h = b & 3;
    const int tid = threadIdx.x;
    const int w = tid >> 6;        // wave 0..3
    const int l = tid & 63;        // lane
    const int q = l >> 4;          // quad 0..3
    const int m = l & 15;          // low lane bits
    const size_t base_q = (size_t)((0 * NH + h) * NN + n) * (NN * HD);
    const size_t base_k = (size_t)((1 * NH + h) * NN + n) * (NN * HD);
    const size_t base_v = (size_t)((2 * NH + h) * NN + n) * (NN * HD);
    const float SCALE = 0.17677669529663687f;  // 1/sqrt(32)
    const f32x4 zero = {0.0f, 0.0f, 0.0f, 0.0f};

    // ---- Stage Q and K into fragment-order LDS (3072 16B slots) ----
    #pragma unroll
    for (int it = 0; it < 12; it++) {
        const int s = tid + it * 256;
        const int isK = s >= 1536;
        const int slot = isK ? (s - 1536) : s;   // 1536 is not pow2; & 1535 would be wrong
        const int t  = slot >> 6;
        const int l2 = slot & 63;
        const int row = t * 16 + (l2 & 15);
        const int off8 = (l2 >> 4) * 8;
        const u16x8 raw = *(const u16x8*)(qkv_t + (isK ? base_k : base_q) +
                                         (size_t)row * HD + off8);
        unsigned short* dst = (isK ? Kf : Qf) + slot * 8;
        *(u16x8*)dst = raw;
    }
    __syncthreads();

    // ---- Pass 1: column sums of exp(scale*S) -> sst[j] = 1/s_j ----
    for (int tt = 0; tt < 6; tt++) {
        const int jt = w + 4 * tt;
        const bf16x8f kb = *(const bf16x8f*)&Kf[jt * 512 + l * 8];
        float s0 = 0.f, s1 = 0.f, s2 = 0.f, s3 = 0.f;
        for (int it = 0; it < 24; it++) {
            const bf16x8f qa = *(const bf16x8f*)&Qf[it * 512 + l * 8];
            const f32x4 c = __builtin_amdgcn_mfma_f32_16x16x32_bf16(qa, kb, zero, 0, 0, 0);
            s0 += __expf(c[0] * SCALE);
            s1 += __expf(c[1] * SCALE);
            s2 += __expf(c[2] * SCALE);
            s3 += __expf(c[3] * SCALE);
        }
        float s = s0 + s1 + s2 + s3;
        s += __shfl_xor(s, 16, 64);
        s += __shfl_xor(s, 32, 64);
        if (q == 0) sst[jt * 16 + m] = 1.0f / s;
    }
    __syncthreads();

    // ---- Pass 2: O = P @ V' (V' = V * 1/s), V staged in quarters ----
    f32x4 oacc[6][2];
    #pragma unroll
    for (int tt = 0; tt < 6; tt++) {
        oacc[tt][0] = zero;
        oacc[tt][1] = zero;
    }

    for (int vr = 0; vr < 4; vr++) {
        // stage Vf: 384 slots (3 chunks x 2 dhalves x 64 lanes)
        for (int s = tid; s < 384; s += 256) {
            const int cl = s >> 7;           // 0..2
            const int dh = (s >> 6) & 1;
            const int l2 = s & 63;
            const int cg = vr * 3 + cl;
            const int j0 = cg * 32 + (l2 >> 4) * 8;
            const int d  = dh * 16 + (l2 & 15);
            ushort4 pk0, pk1;
            {
                const unsigned short* vp = qkv_t + base_v + (size_t)j0 * HD + d;
                pk0.x = f2b(b2f(vp[0 * HD]) * sst[j0 + 0]);
                pk0.y = f2b(b2f(vp[1 * HD]) * sst[j0 + 1]);
                pk0.z = f2b(b2f(vp[2 * HD]) * sst[j0 + 2]);
                pk0.w = f2b(b2f(vp[3 * HD]) * sst[j0 + 3]);
                pk1.x = f2b(b2f(vp[4 * HD]) * sst[j0 + 4]);
                pk1.y = f2b(b2f(vp[5 * HD]) * sst[j0 + 5]);
                pk1.z = f2b(b2f(vp[6 * HD]) * sst[j0 + 6]);
                pk1.w = f2b(b2f(vp[7 * HD]) * sst[j0 + 7]);
            }
            unsigned short* dst = Vf + ((cl * 2 + dh) * 64 + l2) * 8;
            *(ushort4*)(dst)     = pk0;
            *(ushort4*)(dst + 4) = pk1;
        }
        __syncthreads();

        for (int cl = 0; cl < 3; cl++) {
            const int cg = vr * 3 + cl;
            const bf16x8f ka0 = *(const bf16x8f*)&Kf[(cg * 2 + 0) * 512 + l * 8];
            const bf16x8f ka1 = *(const bf16x8f*)&Kf[(cg * 2 + 1) * 512 + l * 8];
            const bf16x8f vb0 = *(const bf16x8f*)&Vf[((cl * 2 + 0) * 64 + l) * 8];
            const bf16x8f vb1 = *(const bf16x8f*)&Vf[((cl * 2 + 1) * 64 + l) * 8];
            #pragma unroll
            for (int tt = 0; tt < 6; tt++) {
                const int it = w + 4 * tt;
                const bf16x8f qb = *(const bf16x8f*)&Qf[it * 512 + l * 8];
                // S^T tiles: rows j (quad*4+reg), cols i (m)
                const f32x4 sT0 = __builtin_amdgcn_mfma_f32_16x16x32_bf16(ka0, qb, zero, 0, 0, 0);
                const f32x4 sT1 = __builtin_amdgcn_mfma_f32_16x16x32_bf16(ka1, qb, zero, 0, 0, 0);
                // P = exp(scale*S): lane (q,m) holds P[i=m][j=q*4+r] (+16 for sT1)
                ushort4 p0, p1;
                p0.x = f2b(__expf(sT0[0] * SCALE));
                p0.y = f2b(__expf(sT0[1] * SCALE));
                p0.z = f2b(__expf(sT0[2] * SCALE));
                p0.w = f2b(__expf(sT0[3] * SCALE));
                p1.x = f2b(__expf(sT1[0] * SCALE));
                p1.y = f2b(__expf(sT1[1] * SCALE));
                p1.z = f2b(__expf(sT1[2] * SCALE));
                p1.w = f2b(__expf(sT1[3] * SCALE));
                *(ushort4*)&Pscr[w][m][q * 4]      = p0;
                *(ushort4*)&Pscr[w][m][16 + q * 4] = p1;
                // Same-wave LDS RAW (cross-lane within wave): fence + drain.
                __asm__ volatile("" ::: "memory");
                __builtin_amdgcn_s_waitcnt(0xC07F);   // lgkmcnt(0), vm/exp don't-care
                // read back as PV A-frag: P[i=m][j=q*8..q*8+7]
                const bf16x8f pa = *(const bf16x8f*)&Pscr[w][m][q * 8];
                __asm__ volatile("" ::: "memory");
                oacc[tt][0] = __builtin_amdgcn_mfma_f32_16x16x32_bf16(pa, vb0, oacc[tt][0], 0, 0, 0);
                oacc[tt][1] = __builtin_amdgcn_mfma_f32_16x16x32_bf16(pa, vb1, oacc[tt][1], 0, 0, 0);
            }
        }
        __syncthreads();
    }

    // ---- Store O: rows i = it*16 + q*4 + r, col d = dt*16 + m ----
    #pragma unroll
    for (int tt = 0; tt < 6; tt++) {
        const int it = w + 4 * tt;
        #pragma unroll
        for (int dt = 0; dt < 2; dt++) {
            #pragma unroll
            for (int r = 0; r < 4; r++) {
                const int i = it * 16 + q * 4 + r;
                attn_out[((size_t)i * NN + n) * CZ + h * HD + dt * 16 + m] = oacc[tt][dt][r];
            }
        }
    }
}

// ---------------------------------------------------------------------------
// Final dual GEMM on MFMA (bf16 inputs, f32 accumulate), in place on out:
//   out = z + sigmoid(LN(z)@gate_w+gate_b) * (attn@out_w + out_b)
// Tile: 64 rows x 128 cols (full N), K = 128 in one shot; 4 waves each own a
// 32-col slice.  Both row operands (LN(z) recomputed from z+mu/rstd, attn
// read from `out`) staged as bf16 into XOR-swizzled LDS (2 x 16 KB).
// W fragments (gate_w, out_w cols) direct global->reg, L2-hot.
// In-place safe: all attn reads land in LDS before the barrier; the block
// owns its 64 rows exclusively.
// ---------------------------------------------------------------------------
__global__ __launch_bounds__(256) void final_mfma_kernel(const float* __restrict__ z,
                                                         const float* __restrict__ mu,
                                                         const float* __restrict__ rstd,
                                                         const float* __restrict__ lnw,
                                                         const float* __restrict__ lnb,
                                                         const float* __restrict__ gate_w,
                                                         const float* __restrict__ gate_b,
                                                         const float* __restrict__ out_w,
                                                         const float* __restrict__ out_b,
                                                         float* out) {
    __shared__ unsigned short Zt[64 * 128];   // LN(z) bf16, swizzled (16 KB)
    __shared__ unsigned short At[64 * 128];   // attn  bf16, swizzled (16 KB)

    const int tid = threadIdx.x;
    const int w = tid >> 6;        // wave = col slice 0..3 (32 cols each)
    const int l = tid & 63;
    const int lm = l & 15;
    const int lq = l >> 4;
    const int row0 = blockIdx.x * 64;

    // ---- stage LN(z) and attn tiles into swizzled LDS as bf16 ----
    #pragma unroll
    for (int it = 0; it < 4; it++) {
        const int s = it * 256 + tid;          // 1024 16B slots
        const int r = s >> 4;                  // 0..63
        const int c = (s & 15) ^ (r & 7);      // inverse swizzle on source chunk
        const int k0 = c * 8;
        const int grow = row0 + r;
        const float m  = mu[grow];
        const float rs = rstd[grow];
        const size_t gi = (size_t)grow * CZ + k0;
        const float4 z0 = *(const float4*)(z + gi);
        const float4 z1 = *(const float4*)(z + gi + 4);
        const float4 a0 = *(const float4*)(out + gi);
        const float4 a1 = *(const float4*)(out + gi + 4);
        const float4 w0 = *(const float4*)(lnw + k0);
        const float4 w1 = *(const float4*)(lnw + k0 + 4);
        const float4 b0 = *(const float4*)(lnb + k0);
        const float4 b1 = *(const float4*)(lnb + k0 + 4);
        u16x8 pz, pa;
        pz[0] = f2b((z0.x - m) * rs * w0.x + b0.x);
        pz[1] = f2b((z0.y - m) * rs * w0.y + b0.y);
        pz[2] = f2b((z0.z - m) * rs * w0.z + b0.z);
        pz[3] = f2b((z0.w - m) * rs * w0.w + b0.w);
        pz[4] = f2b((z1.x - m) * rs * w1.x + b1.x);
        pz[5] = f2b((z1.y - m) * rs * w1.y + b1.y);
        pz[6] = f2b((z1.z - m) * rs * w1.z + b1.z);
        pz[7] = f2b((z1.w - m) * rs * w1.w + b1.w);
        pa[0] = f2b(a0.x); pa[1] = f2b(a0.y); pa[2] = f2b(a0.z); pa[3] = f2b(a0.w);
        pa[4] = f2b(a1.x); pa[5] = f2b(a1.y); pa[6] = f2b(a1.z); pa[7] = f2b(a1.w);
        *(u16x8*)&Zt[s * 8] = pz;
        *(u16x8*)&At[s * 8] = pa;
    }

    // ---- W fragments direct global->reg (gate_w and out_w, 32-col slice) ----
    // A-frag layout: m = lane&15 (out-col), k = kk*32 + (lane>>4)*8 + j.
    bf16x8f gw[2][4], ow[2][4];
    #pragma unroll
    for (int fm = 0; fm < 2; fm++) {
        const int gcol = w * 32 + fm * 16 + lm;
        #pragma unroll
        for (int kk = 0; kk < 4; kk++) {
            const int kb = kk * 32 + lq * 8;
            #pragma unroll
            for (int j = 0; j < 8; j++) {
                gw[fm][kk][j] = (short)f2b(gate_w[(size_t)(kb + j) * CZ + gcol]);
                ow[fm][kk][j] = (short)f2b(out_w [(size_t)(kb + j) * CZ + gcol]);
            }
        }
    }

    __syncthreads();

    // ---- MFMA main: 4 k-steps x 2 col-frags x 4 row-frags x 2 GEMMs ----
    f32x4 acc1[2][4], acc2[2][4];
    #pragma unroll
    for (int fm = 0; fm < 2; fm++)
        #pragma unroll
        for (int fn = 0; fn < 4; fn++) {
            acc1[fm][fn] = (f32x4){0.0f, 0.0f, 0.0f, 0.0f};
            acc2[fm][fn] = (f32x4){0.0f, 0.0f, 0.0f, 0.0f};
        }

    #pragma unroll
    for (int kk = 0; kk < 4; kk++) {
        bf16x8f bz[4], ba[4];
        #pragma unroll
        for (int fn = 0; fn < 4; fn++) {
            const int r = fn * 16 + lm;
            const int ch = (kk * 4 + lq) ^ (r & 7);     // swizzled chunk index
            bz[fn] = *(const bf16x8f*)&Zt[(r * 16 + ch) * 8];
            ba[fn] = *(const bf16x8f*)&At[(r * 16 + ch) * 8];
        }
        #pragma unroll
        for (int fm = 0; fm < 2; fm++)
            #pragma unroll
            for (int fn = 0; fn < 4; fn++) {
                acc1[fm][fn] = __builtin_amdgcn_mfma_f32_16x16x32_bf16(gw[fm][kk], bz[fn],
                                                                       acc1[fm][fn], 0, 0, 0);
                acc2[fm][fn] = __builtin_amdgcn_mfma_f32_16x16x32_bf16(ow[fm][kk], ba[fn],
                                                                       acc2[fm][fn], 0, 0, 0);
            }
    }

    // ---- epilogue: sigmoid-gate + residual, float4 in-place store ----
    #pragma unroll
    for (int fm = 0; fm < 2; fm++) {
        const int gc = w * 32 + fm * 16 + lq * 4;       // out-col of reg 0
        const float4 gb4 = *(const float4*)(gate_b + gc);
        const float4 ob4 = *(const float4*)(out_b + gc);
        #pragma unroll
        for (int fn = 0; fn < 4; fn++) {
            const int grow = row0 + fn * 16 + lm;
            const size_t idx = (size_t)grow * CZ + gc;
            const float4 z4 = *(const float4*)(z + idx);
            float4 o;
            o.x = z4.x + (1.0f / (1.0f + __expf(-(acc1[fm][fn][0] + gb4.x)))) * (acc2[fm][fn][0] + ob4.x);
            o.y = z4.y + (1.0f / (1.0f + __expf(-(acc1[fm][fn][1] + gb4.y)))) * (acc2[fm][fn][1] + ob4.y);
            o.z = z4.z + (1.0f / (1.0f + __expf(-(acc1[fm][fn][2] + gb4.z)))) * (acc2[fm][fn][2] + ob4.z);
            o.w = z4.w + (1.0f / (1.0f + __expf(-(acc1[fm][fn][3] + gb4.w)))) * (acc2[fm][fn][3] + ob4.w);
            *(float4*)(out + idx) = o;
        }
    }
}

// ---------------------------------------------------------------------------
extern "C" void kernel_launch(void* const* d_in, const int* in_sizes, int n_in,
                              void* d_out, int out_size, void* d_ws, size_t ws_size,
                              hipStream_t stream) {
    const float* z      = (const float*)d_in[0];
    const float* ln_w   = (const float*)d_in[1];
    const float* ln_b   = (const float*)d_in[2];
    const float* qkv_w  = (const float*)d_in[3];
    const float* qkv_b  = (const float*)d_in[4];
    const float* out_w  = (const float*)d_in[5];
    const float* out_b  = (const float*)d_in[6];
    const float* gate_w = (const float*)d_in[7];
    const float* gate_b = (const float*)d_in[8];
    float* out = (float*)d_out;

    // Workspace: mu + rstd (f32) + qkv_t (bf16) ~= 114 MiB
    float* ws = (float*)d_ws;
    float* mu_buf   = ws;
    float* rstd_buf = ws + MROWS;
    unsigned short* qkv_t = (unsigned short*)(ws + 2 * MROWS);

    ln_stats_kernel<<<MROWS / 4, 256, 0, stream>>>(z, mu_buf, rstd_buf);
    qkv_gemm_mfma_kernel<<<dim3(6, MROWS / 128), 256, 0, stream>>>(z, mu_buf, rstd_buf,
                                                                   ln_w, ln_b, qkv_w, qkv_b, qkv_t);
    attn_mfma_kernel<<<NN * NH, 256, 0, stream>>>(qkv_t, out);
    final_mfma_kernel<<<MROWS / 64, 256, 0, stream>>>(z, mu_buf, rstd_buf, ln_w, ln_b,
                                                      gate_w, gate_b, out_w, out_b, out);
}